// Round 6
// baseline (158.960 us; speedup 1.0000x reference)
//
#include <hip/hip_runtime.h>

typedef float f4 __attribute__((ext_vector_type(4)));
typedef float f32x4 __attribute__((ext_vector_type(4)));
typedef short bf16x8 __attribute__((ext_vector_type(8)));
typedef unsigned short u16x8 __attribute__((ext_vector_type(8)));

static __device__ __forceinline__ unsigned short f2bf(float f) {
    unsigned int x = __builtin_bit_cast(unsigned int, f);
    x = (x + 0x7fffu + ((x >> 16) & 1u)) >> 16;
    return (unsigned short)x;
}
static __device__ __forceinline__ float bf2f(unsigned short h) {
    unsigned int x = ((unsigned int)h) << 16;
    return __builtin_bit_cast(float, x);
}

// async 16B global->LDS DMA (LDS dest = wave-uniform base + lane*16)
static __device__ __forceinline__ void gll16(const unsigned short* g, unsigned short* l) {
    __builtin_amdgcn_global_load_lds(
        (__attribute__((address_space(1))) void*)(g),
        (__attribute__((address_space(3))) void*)(l), 16, 0, 0);
}

// ---------------- convert: f32 -> (bf16 hi, bf16 lo) planes, 5 tensors fused
struct CvtJob { const float* src; unsigned short* hi; unsigned short* lo; int n8; };

__global__ __launch_bounds__(256) void convert_kernel(
    CvtJob j0, CvtJob j1, CvtJob j2, CvtJob j3, CvtJob j4, int total8)
{
    CvtJob jobs[5] = { j0, j1, j2, j3, j4 };
    int cum1 = j0.n8, cum2 = cum1 + j1.n8, cum3 = cum2 + j2.n8, cum4 = cum3 + j3.n8;
    for (int g = blockIdx.x * blockDim.x + threadIdx.x; g < total8;
         g += gridDim.x * blockDim.x) {
        int ji, base;
        if      (g < cum1) { ji = 0; base = 0; }
        else if (g < cum2) { ji = 1; base = cum1; }
        else if (g < cum3) { ji = 2; base = cum2; }
        else if (g < cum4) { ji = 3; base = cum3; }
        else               { ji = 4; base = cum4; }
        const CvtJob& J = jobs[ji];
        int idx = (g - base) * 8;
        f4 a = *(const f4*)(J.src + idx);
        f4 b = *(const f4*)(J.src + idx + 4);
        u16x8 hv, lv;
        float s[8] = { a.x, a.y, a.z, a.w, b.x, b.y, b.z, b.w };
        #pragma unroll
        for (int i = 0; i < 8; ++i) {
            unsigned short h = f2bf(s[i]);
            hv[i] = h;
            lv[i] = f2bf(s[i] - bf2f(h));
        }
        *(u16x8*)(J.hi + idx) = hv;
        *(u16x8*)(J.lo + idx) = lv;
    }
}

// ---------------- merged split-bf16 MFMA GEMM, 128x128 tiles, async 2-phase,
//                  XCD-chunked block swizzle
struct GJob {
    const unsigned short *Ah, *Al, *Wh, *Wl;
    int lda, ldw;
    const float* bias;
    float* Cf;
    unsigned short *Ch, *Cl;
    int N, K, nbx;
};

// LDS frag offset (shorts) for row r, true 16B-slot s (source-swizzle inverse)
static __device__ __forceinline__ int fragoff(int r, int s) {
    return r * 32 + ((s ^ ((r >> 1) & 3)) << 3);
}

template<bool SPLIT_OUT>
__global__ __launch_bounds__(256, 2) void gemm128(GJob j0, GJob j1, int nblk0)
{
    // 2 buffers x 4 planes (Ah,Al,Wh,Wl) x [128 rows x 32 k] bf16 = 64 KB
    __shared__ unsigned short lds[2][4][128 * 32];

    const bool first = (int)blockIdx.x < nblk0;
    const GJob J = first ? j0 : j1;
    const int raw  = first ? (int)blockIdx.x : (int)blockIdx.x - nblk0;
    const int nblk = first ? nblk0 : ((int)gridDim.x - nblk0);
    // XCD-chunked swizzle (nblk % 8 == 0 for all jobs): XCD r gets q
    // consecutive tiles (m-fastest) -> shared W n-panel stays in its L2.
    const int q = nblk >> 3;
    const int local = (raw & 7) * q + (raw >> 3);
    const int m0 = (local % J.nbx) * 128;
    const int n0 = (local / J.nbx) * 128;

    const int tid  = threadIdx.x;
    const int lane = tid & 63;
    const int wid  = tid >> 6;
    const int wr   = wid >> 1, wc = wid & 1;
    const int lrow = lane & 15;
    const int s    = lane >> 4;

    // staging: each wave issues 8 DMAs/K-step; one DMA = 16 rows x 32 k.
    // Wave wid covers rows [wid*32, wid*32+32) (two 16-row halves) per plane.
    const int rr = lane >> 2;              // row within DMA (0..15)
    const int g0 = wid * 32 + rr;
    const int g1 = g0 + 16;
    const int sl0 = (lane & 3) ^ ((g0 >> 1) & 3);   // pre-swizzled 16B slot
    const int sl1 = (lane & 3) ^ ((g1 >> 1) & 3);
    const size_t gA0 = (size_t)(m0 + g0) * J.lda + sl0 * 8;
    const size_t gA1 = (size_t)(m0 + g1) * J.lda + sl1 * 8;
    const size_t gW0 = (size_t)(n0 + g0) * J.ldw + sl0 * 8;
    const size_t gW1 = (size_t)(n0 + g1) * J.ldw + sl1 * 8;
    const int l0 = (wid * 32) * 32;        // LDS short-offset of half 0
    const int l1 = l0 + 16 * 32;

#define STAGE(buf, k0) do { \
    gll16(J.Ah + gA0 + (k0), &lds[buf][0][l0]); \
    gll16(J.Ah + gA1 + (k0), &lds[buf][0][l1]); \
    gll16(J.Al + gA0 + (k0), &lds[buf][1][l0]); \
    gll16(J.Al + gA1 + (k0), &lds[buf][1][l1]); \
    gll16(J.Wh + gW0 + (k0), &lds[buf][2][l0]); \
    gll16(J.Wh + gW1 + (k0), &lds[buf][2][l1]); \
    gll16(J.Wl + gW0 + (k0), &lds[buf][3][l0]); \
    gll16(J.Wl + gW1 + (k0), &lds[buf][3][l1]); \
} while (0)

    f32x4 acc[4][4];
    #pragma unroll
    for (int i = 0; i < 4; ++i)
        #pragma unroll
        for (int j = 0; j < 4; ++j) acc[i][j] = (f32x4){0.f, 0.f, 0.f, 0.f};

    const int nt = J.K / 32;

    STAGE(0, 0);
    asm volatile("s_waitcnt vmcnt(0)" ::: "memory");
    __syncthreads();

    int cur = 0;
    for (int t = 0; t < nt; ++t) {
        if (t + 1 < nt) STAGE(cur ^ 1, (t + 1) * 32);

        bf16x8 ah[4], al[4], wh[4], wl[4];
        #pragma unroll
        for (int i = 0; i < 4; ++i) {
            const int ra = wr * 64 + i * 16 + lrow;
            const int rw = wc * 64 + i * 16 + lrow;
            ah[i] = *(const bf16x8*)&lds[cur][0][fragoff(ra, s)];
            al[i] = *(const bf16x8*)&lds[cur][1][fragoff(ra, s)];
            wh[i] = *(const bf16x8*)&lds[cur][2][fragoff(rw, s)];
            wl[i] = *(const bf16x8*)&lds[cur][3][fragoff(rw, s)];
        }
        #pragma unroll
        for (int i = 0; i < 4; ++i)
            #pragma unroll
            for (int j = 0; j < 4; ++j) {
                acc[i][j] = __builtin_amdgcn_mfma_f32_16x16x32_bf16(ah[i], wh[j], acc[i][j], 0, 0, 0);
                acc[i][j] = __builtin_amdgcn_mfma_f32_16x16x32_bf16(ah[i], wl[j], acc[i][j], 0, 0, 0);
                acc[i][j] = __builtin_amdgcn_mfma_f32_16x16x32_bf16(al[i], wh[j], acc[i][j], 0, 0, 0);
            }

        if (t + 1 < nt) {
            asm volatile("s_waitcnt vmcnt(0)" ::: "memory");
            __syncthreads();
            cur ^= 1;
        }
    }
#undef STAGE

    // epilogue: C/D layout col = lane&15, row = (lane>>4)*4 + r
    #pragma unroll
    for (int i = 0; i < 4; ++i) {
        const int rbase = m0 + wr * 64 + i * 16 + (lane >> 4) * 4;
        #pragma unroll
        for (int j = 0; j < 4; ++j) {
            const int col = n0 + wc * 64 + j * 16 + (lane & 15);
            const float bv = J.bias ? J.bias[col] : 0.f;
            #pragma unroll
            for (int r = 0; r < 4; ++r) {
                float v = acc[i][j][r] + bv;
                size_t off = (size_t)(rbase + r) * J.N + col;
                if (SPLIT_OUT) {
                    unsigned short h = f2bf(v);
                    J.Ch[off] = h;
                    J.Cl[off] = f2bf(v - bf2f(h));
                } else {
                    J.Cf[off] = v;
                }
            }
        }
    }
}

// ---------------- broadcast add: out[(b,t),u,:] = X[(b,t),:] + Y[(b,u),:]
__global__ __launch_bounds__(256) void bcast_kernel(
    const float* __restrict__ X, const float* __restrict__ Y,
    float* __restrict__ out, int T, int U)
{
    const int Vq  = 256;           // 1024 / 4
    const int bt  = blockIdx.x;
    const int b   = bt / T;
    const int tid = threadIdx.x;

    const f4* X4 = (const f4*)X;
    const f4* Y4 = (const f4*)Y + (size_t)b * U * Vq;
    f4* O4 = (f4*)out + (size_t)bt * U * Vq;

    f4 x = X4[(size_t)bt * Vq + tid];
    #pragma unroll 4
    for (int u = 0; u < U; ++u) {
        f4 y = Y4[u * Vq + tid];
        f4 r = { x.x + y.x, x.y + y.y, x.z + y.z, x.w + y.w };
        __builtin_nontemporal_store(r, &O4[u * Vq + tid]);
    }
}

extern "C" void kernel_launch(void* const* d_in, const int* in_sizes, int n_in,
                              void* d_out, int out_size, void* d_ws, size_t ws_size,
                              hipStream_t stream) {
    (void)in_sizes; (void)n_in; (void)out_size; (void)ws_size;

    const int B = 8, T = 256, U = 64;
    const int ENC = 512, DEC = 640, J = 512, V = 1024;
    const int MT = B * T;   // 2048
    const int MU = B * U;   // 512

    const float* enc    = (const float*)d_in[0];
    const float* pred   = (const float*)d_in[1];
    const float* W_enc  = (const float*)d_in[2];
    const float* b_enc  = (const float*)d_in[3];
    const float* W_pred = (const float*)d_in[4];
    const float* b_pred = (const float*)d_in[5];
    const float* W_out  = (const float*)d_in[6];
    const float* b_out  = (const float*)d_in[7];
    float* out = (float*)d_out;

    const int n_enc  = MT * ENC;
    const int n_pred = MU * DEC;
    const int n_We   = J * ENC;
    const int n_Wp   = J * DEC;
    const int n_Wo   = V * 2 * J;
    const int n_e    = MT * J;
    const int n_p    = MU * J;

    unsigned short* w = (unsigned short*)d_ws;
    unsigned short* enc_h  = w;
    unsigned short* enc_l  = enc_h + n_enc;
    unsigned short* pred_h = enc_l + n_enc;
    unsigned short* pred_l = pred_h + n_pred;
    unsigned short* We_h   = pred_l + n_pred;
    unsigned short* We_l   = We_h + n_We;
    unsigned short* Wp_h   = We_l + n_We;
    unsigned short* Wp_l   = Wp_h + n_Wp;
    unsigned short* Wo_h   = Wp_l + n_Wp;
    unsigned short* Wo_l   = Wo_h + n_Wo;
    unsigned short* e_h    = Wo_l + n_Wo;
    unsigned short* e_l    = e_h + n_e;
    unsigned short* p_h    = e_l + n_e;
    unsigned short* p_l    = p_h + n_p;
    float* ws_X = (float*)(p_l + n_p);          // (MT, V)
    float* ws_Y = ws_X + (size_t)MT * V;        // (MU, V)

    // 1) convert all f32 inputs to bf16 hi/lo planes
    CvtJob j0 = { enc,    enc_h,  enc_l,  n_enc  / 8 };
    CvtJob j1 = { pred,   pred_h, pred_l, n_pred / 8 };
    CvtJob j2 = { W_enc,  We_h,   We_l,   n_We   / 8 };
    CvtJob j3 = { W_pred, Wp_h,   Wp_l,   n_Wp   / 8 };
    CvtJob j4 = { W_out,  Wo_h,   Wo_l,   n_Wo   / 8 };
    const int total8 = (n_enc + n_pred + n_We + n_Wp + n_Wo) / 8;
    convert_kernel<<<(total8 + 255) / 256, 256, 0, stream>>>(j0, j1, j2, j3, j4, total8);

    // 2) merged e + p GEMMs (split-bf16 planes out), 128x128 tiles
    GJob je = { enc_h, enc_l, We_h, We_l, ENC, ENC, b_enc,
                nullptr, e_h, e_l, J, ENC, MT / 128 };
    GJob jp = { pred_h, pred_l, Wp_h, Wp_l, DEC, DEC, b_pred,
                nullptr, p_h, p_l, J, DEC, MU / 128 };
    const int nbe = (MT / 128) * (J / 128);   // 64
    const int nbp = (MU / 128) * (J / 128);   // 16
    gemm128<true><<<nbe + nbp, 256, 0, stream>>>(je, jp, nbe);

    // 3) merged X + Y GEMMs (f32 out), 128x128 tiles
    GJob jx = { e_h, e_l, Wo_h, Wo_l, J, 2 * J, b_out,
                ws_X, nullptr, nullptr, V, J, MT / 128 };
    GJob jy = { p_h, p_l, Wo_h + J, Wo_l + J, J, 2 * J, nullptr,
                ws_Y, nullptr, nullptr, V, J, MU / 128 };
    const int nbx = (MT / 128) * (V / 128);   // 128
    const int nby = (MU / 128) * (V / 128);   // 32
    gemm128<false><<<nbx + nby, 256, 0, stream>>>(jx, jy, nbx);

    // 4) out = X broadcast + Y
    bcast_kernel<<<dim3(B * T), 256, 0, stream>>>(ws_X, ws_Y, out, T, U);
}

// Round 7
// 136.296 us; speedup vs baseline: 1.1663x; 1.1663x over previous
//
#include <hip/hip_runtime.h>

typedef float f4 __attribute__((ext_vector_type(4)));
typedef float f32x4 __attribute__((ext_vector_type(4)));
typedef short bf16x8 __attribute__((ext_vector_type(8)));
typedef unsigned short u16x8 __attribute__((ext_vector_type(8)));

static __device__ __forceinline__ unsigned short f2bf(float f) {
    unsigned int x = __builtin_bit_cast(unsigned int, f);
    x = (x + 0x7fffu + ((x >> 16) & 1u)) >> 16;
    return (unsigned short)x;
}
static __device__ __forceinline__ float bf2f(unsigned short h) {
    unsigned int x = ((unsigned int)h) << 16;
    return __builtin_bit_cast(float, x);
}

// async 16B global->LDS DMA (LDS dest = wave-uniform base + lane*16)
static __device__ __forceinline__ void gll16(const unsigned short* g, unsigned short* l) {
    __builtin_amdgcn_global_load_lds(
        (__attribute__((address_space(1))) void*)(g),
        (__attribute__((address_space(3))) void*)(l), 16, 0, 0);
}

// LDS frag offset (shorts) for row r, true 16B-slot s (involution, both sides)
static __device__ __forceinline__ int fragoff(int r, int s) {
    return r * 32 + ((s ^ ((r >> 1) & 3)) << 3);
}

// ================= stage 1: merged {e,p} GEMM with in-staging f32->split-bf16
//                   conversion, + W_out conversion blocks in same launch
struct GJobF {
    const float *A, *W;
    int lda, ldw;
    const float* bias;
    unsigned short *Ch, *Cl;
    int N, K, nbx;
};

__global__ __launch_bounds__(256, 3) void gemmcvt64(
    GJobF j0, GJobF j1, int nblk0, int nblk1,
    const float* __restrict__ Wo, unsigned short* __restrict__ Wo_h,
    unsigned short* __restrict__ Wo_l, int nWo8)
{
    __shared__ unsigned short lds[2][4][64 * 32];   // 2 bufs x {Ah,Al,Wh,Wl}

    const int bid = blockIdx.x;
    const int tid = threadIdx.x;

    if (bid >= nblk0 + nblk1) {
        // ---- W_out f32 -> hi/lo planes (grid-stride over 8-elem chunks)
        const int nblkc = (int)gridDim.x - nblk0 - nblk1;
        for (int g = (bid - nblk0 - nblk1) * 256 + tid; g < nWo8; g += nblkc * 256) {
            const int idx = g * 8;
            f4 a = *(const f4*)(Wo + idx);
            f4 b = *(const f4*)(Wo + idx + 4);
            u16x8 hv, lv;
            float s[8] = { a.x, a.y, a.z, a.w, b.x, b.y, b.z, b.w };
            #pragma unroll
            for (int i = 0; i < 8; ++i) {
                unsigned short h = f2bf(s[i]);
                hv[i] = h;
                lv[i] = f2bf(s[i] - bf2f(h));
            }
            *(u16x8*)(Wo_h + idx) = hv;
            *(u16x8*)(Wo_l + idx) = lv;
        }
        return;
    }

    const bool first = bid < nblk0;
    const GJobF J = first ? j0 : j1;
    const int local = first ? bid : bid - nblk0;
    const int m0 = (local % J.nbx) * 64;
    const int n0 = (local / J.nbx) * 64;

    const int lane = tid & 63;
    const int wid  = tid >> 6;
    const int wr   = wid >> 1, wc = wid & 1;
    const int lrow = lane & 15;
    const int s    = lane >> 4;

    // staging map: thread -> (row 0..63, true slot 0..3); swizzled LDS write
    const int row  = tid >> 2, slot = tid & 3;
    const int woff = fragoff(row, slot);
    const float* pA = J.A + (size_t)(m0 + row) * J.lda + slot * 8;
    const float* pW = J.W + (size_t)(n0 + row) * J.ldw + slot * 8;

    f4 ra0, ra1, rw0, rw1;

#define LOADREGS(k0) do { \
    ra0 = *(const f4*)(pA + (k0));     ra1 = *(const f4*)(pA + (k0) + 4); \
    rw0 = *(const f4*)(pW + (k0));     rw1 = *(const f4*)(pW + (k0) + 4); \
} while (0)

#define CVTWRITE(buf) do { \
    u16x8 ha, la, hw, lw; \
    float sa[8] = { ra0.x, ra0.y, ra0.z, ra0.w, ra1.x, ra1.y, ra1.z, ra1.w }; \
    float sw[8] = { rw0.x, rw0.y, rw0.z, rw0.w, rw1.x, rw1.y, rw1.z, rw1.w }; \
    _Pragma("unroll") \
    for (int i = 0; i < 8; ++i) { \
        unsigned short h = f2bf(sa[i]); \
        ha[i] = h; la[i] = f2bf(sa[i] - bf2f(h)); \
        h = f2bf(sw[i]); \
        hw[i] = h; lw[i] = f2bf(sw[i] - bf2f(h)); \
    } \
    *(u16x8*)&lds[buf][0][woff] = ha; \
    *(u16x8*)&lds[buf][1][woff] = la; \
    *(u16x8*)&lds[buf][2][woff] = hw; \
    *(u16x8*)&lds[buf][3][woff] = lw; \
} while (0)

    f32x4 acc[2][2];
    #pragma unroll
    for (int i = 0; i < 2; ++i)
        #pragma unroll
        for (int j = 0; j < 2; ++j) acc[i][j] = (f32x4){0.f, 0.f, 0.f, 0.f};

    const int nt = J.K / 32;

    LOADREGS(0);
    CVTWRITE(0);
    __syncthreads();

    int cur = 0;
    for (int t = 0; t < nt; ++t) {
        if (t + 1 < nt) LOADREGS((t + 1) * 32);

        bf16x8 ah[2], al[2], wh[2], wl[2];
        #pragma unroll
        for (int i = 0; i < 2; ++i) {
            const int ra = wr * 32 + i * 16 + lrow;
            const int rw = wc * 32 + i * 16 + lrow;
            ah[i] = *(const bf16x8*)&lds[cur][0][fragoff(ra, s)];
            al[i] = *(const bf16x8*)&lds[cur][1][fragoff(ra, s)];
            wh[i] = *(const bf16x8*)&lds[cur][2][fragoff(rw, s)];
            wl[i] = *(const bf16x8*)&lds[cur][3][fragoff(rw, s)];
        }
        #pragma unroll
        for (int i = 0; i < 2; ++i)
            #pragma unroll
            for (int j = 0; j < 2; ++j) {
                acc[i][j] = __builtin_amdgcn_mfma_f32_16x16x32_bf16(ah[i], wh[j], acc[i][j], 0, 0, 0);
                acc[i][j] = __builtin_amdgcn_mfma_f32_16x16x32_bf16(ah[i], wl[j], acc[i][j], 0, 0, 0);
                acc[i][j] = __builtin_amdgcn_mfma_f32_16x16x32_bf16(al[i], wh[j], acc[i][j], 0, 0, 0);
            }

        if (t + 1 < nt) {
            CVTWRITE(cur ^ 1);
            __syncthreads();
            cur ^= 1;
        }
    }
#undef LOADREGS
#undef CVTWRITE

    // epilogue: split-bf16 planes out; C/D layout col=lane&15, row=(lane>>4)*4+r
    #pragma unroll
    for (int i = 0; i < 2; ++i) {
        const int rbase = m0 + wr * 32 + i * 16 + (lane >> 4) * 4;
        #pragma unroll
        for (int j = 0; j < 2; ++j) {
            const int col = n0 + wc * 32 + j * 16 + (lane & 15);
            const float bv = J.bias[col];
            #pragma unroll
            for (int r = 0; r < 4; ++r) {
                float v = acc[i][j][r] + bv;
                size_t off = (size_t)(rbase + r) * J.N + col;
                unsigned short h = f2bf(v);
                J.Ch[off] = h;
                J.Cl[off] = f2bf(v - bf2f(h));
            }
        }
    }
}

// ================= stage 2: merged {X,Y} split-bf16 GEMM (planes in, f32 out)
struct GJob {
    const unsigned short *Ah, *Al, *Wh, *Wl;
    int lda, ldw;
    const float* bias;
    float* Cf;
    int N, K, nbx;
};

__global__ __launch_bounds__(256, 3) void gemm64(GJob j0, GJob j1, int nblk0)
{
    __shared__ unsigned short lds[2][4][64 * 32];

    const bool first = (int)blockIdx.x < nblk0;
    const GJob J = first ? j0 : j1;
    const int local = first ? (int)blockIdx.x : (int)blockIdx.x - nblk0;
    const int m0 = (local % J.nbx) * 64;
    const int n0 = (local / J.nbx) * 64;

    const int tid  = threadIdx.x;
    const int lane = tid & 63;
    const int wid  = tid >> 6;
    const int wr   = wid >> 1, wc = wid & 1;
    const int lrow = lane & 15;
    const int s    = lane >> 4;

    // DMA staging: pre-swizzled global source slot, linear LDS dest
    const int srow  = wid * 16 + (lane >> 2);
    const int sslot = (lane & 3) ^ ((srow >> 1) & 3);
    const size_t gA = (size_t)(m0 + srow) * J.lda + sslot * 8;
    const size_t gW = (size_t)(n0 + srow) * J.ldw + sslot * 8;

    f32x4 acc[2][2];
    #pragma unroll
    for (int i = 0; i < 2; ++i)
        #pragma unroll
        for (int j = 0; j < 2; ++j) acc[i][j] = (f32x4){0.f, 0.f, 0.f, 0.f};

    const int nt = J.K / 32;

    gll16(J.Ah + gA, &lds[0][0][wid * 512]);
    gll16(J.Al + gA, &lds[0][1][wid * 512]);
    gll16(J.Wh + gW, &lds[0][2][wid * 512]);
    gll16(J.Wl + gW, &lds[0][3][wid * 512]);
    asm volatile("s_waitcnt vmcnt(0)" ::: "memory");
    __syncthreads();

    int cur = 0;
    for (int t = 0; t < nt; ++t) {
        if (t + 1 < nt) {
            const int k0 = (t + 1) * 32;
            gll16(J.Ah + gA + k0, &lds[cur ^ 1][0][wid * 512]);
            gll16(J.Al + gA + k0, &lds[cur ^ 1][1][wid * 512]);
            gll16(J.Wh + gW + k0, &lds[cur ^ 1][2][wid * 512]);
            gll16(J.Wl + gW + k0, &lds[cur ^ 1][3][wid * 512]);
        }

        bf16x8 ah[2], al[2], wh[2], wl[2];
        #pragma unroll
        for (int i = 0; i < 2; ++i) {
            const int ra = wr * 32 + i * 16 + lrow;
            const int rw = wc * 32 + i * 16 + lrow;
            ah[i] = *(const bf16x8*)&lds[cur][0][fragoff(ra, s)];
            al[i] = *(const bf16x8*)&lds[cur][1][fragoff(ra, s)];
            wh[i] = *(const bf16x8*)&lds[cur][2][fragoff(rw, s)];
            wl[i] = *(const bf16x8*)&lds[cur][3][fragoff(rw, s)];
        }
        #pragma unroll
        for (int i = 0; i < 2; ++i)
            #pragma unroll
            for (int j = 0; j < 2; ++j) {
                acc[i][j] = __builtin_amdgcn_mfma_f32_16x16x32_bf16(ah[i], wh[j], acc[i][j], 0, 0, 0);
                acc[i][j] = __builtin_amdgcn_mfma_f32_16x16x32_bf16(ah[i], wl[j], acc[i][j], 0, 0, 0);
                acc[i][j] = __builtin_amdgcn_mfma_f32_16x16x32_bf16(al[i], wh[j], acc[i][j], 0, 0, 0);
            }

        if (t + 1 < nt) {
            asm volatile("s_waitcnt vmcnt(0)" ::: "memory");
            __syncthreads();
            cur ^= 1;
        }
    }

    #pragma unroll
    for (int i = 0; i < 2; ++i) {
        const int rbase = m0 + wr * 32 + i * 16 + (lane >> 4) * 4;
        #pragma unroll
        for (int j = 0; j < 2; ++j) {
            const int col = n0 + wc * 32 + j * 16 + (lane & 15);
            const float bv = J.bias ? J.bias[col] : 0.f;
            #pragma unroll
            for (int r = 0; r < 4; ++r)
                J.Cf[(size_t)(rbase + r) * J.N + col] = acc[i][j][r] + bv;
        }
    }
}

// ================= stage 3: out[(b,t),u,:] = X[(b,t),:] + Y[(b,u),:]
__global__ __launch_bounds__(256) void bcast_kernel(
    const float* __restrict__ X, const float* __restrict__ Y,
    float* __restrict__ out, int T, int U)
{
    const int Vq  = 256;           // 1024 / 4
    const int bt  = blockIdx.x;
    const int b   = bt / T;
    const int tid = threadIdx.x;

    const f4* X4 = (const f4*)X;
    const f4* Y4 = (const f4*)Y + (size_t)b * U * Vq;
    f4* O4 = (f4*)out + (size_t)bt * U * Vq;

    f4 x = X4[(size_t)bt * Vq + tid];
    #pragma unroll 4
    for (int u = 0; u < U; ++u) {
        f4 y = Y4[u * Vq + tid];
        f4 r = { x.x + y.x, x.y + y.y, x.z + y.z, x.w + y.w };
        __builtin_nontemporal_store(r, &O4[u * Vq + tid]);
    }
}

extern "C" void kernel_launch(void* const* d_in, const int* in_sizes, int n_in,
                              void* d_out, int out_size, void* d_ws, size_t ws_size,
                              hipStream_t stream) {
    (void)in_sizes; (void)n_in; (void)out_size; (void)ws_size;

    const int B = 8, T = 256, U = 64;
    const int ENC = 512, DEC = 640, J = 512, V = 1024;
    const int MT = B * T;   // 2048
    const int MU = B * U;   // 512

    const float* enc    = (const float*)d_in[0];
    const float* pred   = (const float*)d_in[1];
    const float* W_enc  = (const float*)d_in[2];
    const float* b_enc  = (const float*)d_in[3];
    const float* W_pred = (const float*)d_in[4];
    const float* b_pred = (const float*)d_in[5];
    const float* W_out  = (const float*)d_in[6];
    const float* b_out  = (const float*)d_in[7];
    float* out = (float*)d_out;

    const int n_Wo = V * 2 * J;   // 1048576
    const int n_e  = MT * J;      // 1048576
    const int n_p  = MU * J;      // 262144

    unsigned short* w = (unsigned short*)d_ws;
    unsigned short* Wo_h = w;
    unsigned short* Wo_l = Wo_h + n_Wo;
    unsigned short* e_h  = Wo_l + n_Wo;
    unsigned short* e_l  = e_h + n_e;
    unsigned short* p_h  = e_l + n_e;
    unsigned short* p_l  = p_h + n_p;
    float* ws_X = (float*)(p_l + n_p);          // (MT, V)
    float* ws_Y = ws_X + (size_t)MT * V;        // (MU, V)

    // 1) merged e + p GEMMs with in-staging conversion + W_out cvt blocks
    GJobF je = { enc,  W_enc,  ENC, ENC, b_enc,  e_h, e_l, J, ENC, MT / 64 };
    GJobF jp = { pred, W_pred, DEC, DEC, b_pred, p_h, p_l, J, DEC, MU / 64 };
    const int nbe = (MT / 64) * (J / 64);   // 256
    const int nbp = (MU / 64) * (J / 64);   // 64
    const int ncv = 64;
    gemmcvt64<<<nbe + nbp + ncv, 256, 0, stream>>>(
        je, jp, nbe, nbp, W_out, Wo_h, Wo_l, n_Wo / 8);

    // 2) merged X + Y GEMMs (planes in, f32 out)
    GJob jx = { e_h, e_l, Wo_h, Wo_l, J, 2 * J, b_out, ws_X, V, J, MT / 64 };
    GJob jy = { p_h, p_l, Wo_h + J, Wo_l + J, J, 2 * J, nullptr, ws_Y, V, J, MU / 64 };
    const int nbx = (MT / 64) * (V / 64);   // 512
    const int nby = (MU / 64) * (V / 64);   // 128
    gemm64<<<nbx + nby, 256, 0, stream>>>(jx, jy, nbx);

    // 3) out = X broadcast + Y
    bcast_kernel<<<dim3(B * T), 256, 0, stream>>>(ws_X, ws_Y, out, T, U);
}